// Round 1
// baseline (644.685 us; speedup 1.0000x reference)
//
#include <hip/hip_runtime.h>
#include <math.h>

#define EPSI 1e-5f

// ---------------- workspace layout (floats) ----------------
// params block
#define P_PARAMS 0
// fused params offsets inside P:
//   A1[96] @0, C1[32] @96, A2[1024] @128, C2[32] @1152,
//   sa[32] @1184, Ca[32] @1216, sb[32] @1248, Cb[32] @1280,
//   fs1[64] @1312, fc1[64] @1376, fs2[64] @1440, fc2[64] @1504
#define P_D1 2048                    // 128*83*83 = 881792
#define P_D2 (P_D1 + 128*83*83)      // 883840, 128*28*28 = 100352
#define P_D3 (P_D2 + 128*28*28)      // 984192, 128*10*10 = 12800
#define P_D4 (P_D3 + 128*10*10)      // 996992, 128*4*4 = 2048
#define P_D5 (P_D4 + 128*4*4)        // 999040, 128*2*2 = 512
#define P_SCORE (P_D5 + 128*2*2)     // 999552, 4*64*256*256 = 16777216 floats
// d (4,32,248,248)=7872512 floats lives at the head of the score region:
// it is consumed by the first downgrade before k_accum overwrites score.
#define P_D  P_SCORE
// total ws floats = 999552 + 16777216 = 17,776,768  (~71 MB)

struct PrepArgs { const float* p[39]; };

// ---------------- prep: fold all affine params ----------------
__global__ void k_prep(PrepArgs a, float* __restrict__ P) {
  int t = threadIdx.x;
  const float *w1=a.p[1],*b1=a.p[2],*w2=a.p[3],*b2=a.p[4],*g1=a.p[5],*bb1=a.p[6],*m1=a.p[7],*v1=a.p[8];
  const float *w3=a.p[9],*b3=a.p[10],*w4=a.p[11],*b4=a.p[12],*g2=a.p[13],*bb2=a.p[14],*m2=a.p[15],*v2=a.p[16];
  for (int i=t;i<96;i+=256){ int o=i/3; float s=g1[o]/sqrtf(v1[o]+EPSI); P[i]=w1[i]*w2[o]*s; }
  for (int o=t;o<32;o+=256){ float s=g1[o]/sqrtf(v1[o]+EPSI); P[96+o]=(b1[o]*w2[o]+b2[o]-m1[o])*s+bb1[o]; }
  for (int i=t;i<1024;i+=256){ int o2=i/32; float s=g2[o2]/sqrtf(v2[o2]+EPSI); P[128+i]=w3[i]*w4[o2]*s; }
  for (int o=t;o<32;o+=256){ float s=g2[o]/sqrtf(v2[o]+EPSI); P[1152+o]=(b3[o]*w4[o]+b4[o]-m2[o])*s+bb2[o]; }
  const float *iag=a.p[21],*iab=a.p[22],*iam=a.p[23],*iav=a.p[24],*iabias=a.p[20];
  for (int c=t;c<32;c+=256){ float s=iag[c]/sqrtf(iav[c]+EPSI); P[1184+c]=s; P[1216+c]=(iabias[0]-iam[c])*s+iab[c]; }
  const float *ibg=a.p[27],*ibb=a.p[28],*ibm=a.p[29],*ibv=a.p[30],*ibbias=a.p[26];
  for (int c=t;c<32;c+=256){ float s=ibg[c]/sqrtf(ibv[c]+EPSI); P[1248+c]=s; P[1280+c]=(ibbias[0]-ibm[c])*s+ibb[c]; }
  const float *f1g=a.p[31],*f1b=a.p[32],*f1m=a.p[33],*f1v=a.p[34];
  for (int c=t;c<64;c+=256){ float s=f1g[c]/sqrtf(f1v[c]+EPSI); P[1312+c]=s; P[1376+c]=f1b[c]-f1m[c]*s; }
  const float *f2g=a.p[35],*f2b=a.p[36],*f2m=a.p[37],*f2v=a.p[38];
  for (int c=t;c<64;c+=256){ float s=f2g[c]/sqrtf(f2v[c]+EPSI); P[1440+c]=s; P[1504+c]=f2b[c]-f2m[c]*s; }
}

// ---------------- quantize + mode-pool(11,1,1) + fused 3->32->32 MLP ----------------
__global__ __launch_bounds__(256) void k_mode_mlp(const float* __restrict__ x,
                                                 const float* __restrict__ P,
                                                 float* __restrict__ dout) {
  __shared__ int qs[3*676];  // 3 channels, 26x26 levels
  int lx = threadIdx.x, ly = threadIdx.y;
  int tid = ly*16 + lx;
  int tx0 = blockIdx.x*16, ty0 = blockIdx.y*16;
  int b = blockIdx.z;
  for (int k = tid; k < 3*676; k += 256) {
    int cch = k/676; int rem = k - cch*676; int r = rem/26; int cc = rem - r*26;
    int gy = ty0 + r - 1, gx = tx0 + cc - 1;
    int q = 0;
    if ((unsigned)gy < 256u && (unsigned)gx < 256u) {
      float v = x[((size_t)(b*3+cch)*256 + gy)*256 + gx];
      q = (int)rintf(v*255.0f/16.0f);   // RNE, matches jnp.round((x*255)/16)
      q = q < 0 ? 0 : (q > 16 ? 16 : q);
    }
    qs[k] = q;
  }
  __syncthreads();
  int oi = ty0 + ly, oj = tx0 + lx;
  if (oi >= 248 || oj >= 248) return;   // no further barriers below

  float md[3];
  #pragma unroll
  for (int cch = 0; cch < 3; cch++) {
    const int* qp = &qs[cch*676 + ly*26 + lx];
    unsigned h0=0,h1=0,h2=0,h3=0,h4=0;   // 20 packed 8-bit counters (17 used)
    #pragma unroll 1
    for (int u = 0; u < 11; u++) {
      #pragma unroll
      for (int v = 0; v < 11; v++) {
        int q = qp[u*26 + v];
        unsigned inc = 1u << ((q & 3) << 3);
        int sel = q >> 2;
        h0 += (sel==0) ? inc : 0u;
        h1 += (sel==1) ? inc : 0u;
        h2 += (sel==2) ? inc : 0u;
        h3 += (sel==3) ? inc : 0u;
        h4 += (sel==4) ? inc : 0u;
      }
    }
    int best = -1, mode = 0;
    #define CHK(l, w) { int cnt = (int)((w >> (((l)&3)*8)) & 255u); if (cnt > best) { best = cnt; mode = (l); } }
    CHK(0,h0) CHK(1,h0) CHK(2,h0) CHK(3,h0)
    CHK(4,h1) CHK(5,h1) CHK(6,h1) CHK(7,h1)
    CHK(8,h2) CHK(9,h2) CHK(10,h2) CHK(11,h2)
    CHK(12,h3) CHK(13,h3) CHK(14,h3) CHK(15,h3)
    CHK(16,h4)
    #undef CHK
    md[cch] = (float)mode * 0.0625f;
  }

  const float* A1 = P;           const float* C1 = P + 96;
  const float* A2 = P + 128;     const float* C2 = P + 1152;
  float h[32];
  #pragma unroll
  for (int o = 0; o < 32; o++) {
    float v = C1[o] + A1[o*3]*md[0] + A1[o*3+1]*md[1] + A1[o*3+2]*md[2];
    h[o] = (v >= 0.f) ? v : 0.01f*v;
  }
  size_t ob = ((size_t)(b*32)*248 + oi)*248 + oj;
  #pragma unroll
  for (int o2 = 0; o2 < 32; o2++) {
    float acc = C2[o2];
    #pragma unroll
    for (int o = 0; o < 32; o++) acc += A2[o2*32+o]*h[o];
    acc = (acc >= 0.f) ? acc : 0.01f*acc;
    dout[ob + (size_t)o2*(248*248)] = acc;
  }
}

// ---------------- shared 3x3 conv, stride 3, pad 1 ----------------
__global__ void k_down(const float* __restrict__ in, float* __restrict__ out,
                       int Hin, int Hout, int total,
                       const float* __restrict__ scw, const float* __restrict__ scb) {
  int idx = blockIdx.x*256 + threadIdx.x;
  if (idx >= total) return;
  int j = idx % Hout; int t2 = idx / Hout; int i = t2 % Hout; int p = t2 / Hout;
  const float* base = in + (size_t)p*Hin*Hin;
  float s = scb[0];
  #pragma unroll
  for (int u = 0; u < 3; u++) {
    int r = 3*i - 1 + u;
    if ((unsigned)r < (unsigned)Hin) {
      #pragma unroll
      for (int v = 0; v < 3; v++) {
        int cc = 3*j - 1 + v;
        if ((unsigned)cc < (unsigned)Hin) s += base[(size_t)r*Hin + cc]*scw[u*3+v];
      }
    }
  }
  out[idx] = s;
}

// ---------------- pyramid: bilinear upsample + dual 5x5 conv + BN/LReLU, 5 iters ----------------
__global__ __launch_bounds__(256) void k_accum(const float* __restrict__ ws,
                                               const float* __restrict__ iaw,
                                               const float* __restrict__ ibw,
                                               float* __restrict__ score) {
  __shared__ __align__(16) float zt[36*36];
  int tid = threadIdx.x;
  int c = blockIdx.y, b = blockIdx.z;
  int ty0 = (blockIdx.x >> 3)*32, tx0 = (blockIdx.x & 7)*32;
  int ly = tid >> 3, lx4 = (tid & 7)*4;
  float sa = ws[1184+c], Ca = ws[1216+c], sb = ws[1248+c], Cb = ws[1280+c];
  float wa[25], wb[25];
  #pragma unroll
  for (int i = 0; i < 25; i++) { wa[i] = iaw[i]; wb[i] = ibw[i]; }
  float accA[4] = {0,0,0,0}, accB[4] = {0,0,0,0};
  const int NS[5] = {83,28,10,4,2};
  const size_t OFF[5] = {P_D1,P_D2,P_D3,P_D4,P_D5};
  #pragma unroll
  for (int it = 0; it < 5; ++it) {
    const int n = NS[it];
    const float* dp = ws + OFF[it] + (size_t)(b*32+c)*(n*n);
    const float inv = (float)n * (1.f/256.f);
    __syncthreads();
    for (int k = tid; k < 1296; k += 256) {
      int zy = k/36, zx = k - zy*36;
      int gy = ty0 + zy - 2, gx = tx0 + zx - 2;
      float z = 0.f;
      if ((unsigned)gy < 256u && (unsigned)gx < 256u) {  // conv zero-pads beyond image
        float fy = ((float)gy + 0.5f)*inv - 0.5f;
        float fx = ((float)gx + 0.5f)*inv - 0.5f;
        float fyf = floorf(fy), fxf = floorf(fx);
        float wy = fy - fyf, wx = fx - fxf;
        int iy = (int)fyf, ix = (int)fxf;
        int y0 = iy < 0 ? 0 : iy;        int y1 = iy+1 > n-1 ? n-1 : iy+1;
        int x0 = ix < 0 ? 0 : ix;        int x1 = ix+1 > n-1 ? n-1 : ix+1;
        const float* r0 = dp + y0*n;     const float* r1 = dp + y1*n;
        float v0 = r0[x0] + wx*(r0[x1]-r0[x0]);
        float v1 = r1[x0] + wx*(r1[x1]-r1[x0]);
        z = v0 + wy*(v1-v0);
      }
      zt[k] = z;
    }
    __syncthreads();
    float zp[40];   // 5 rows x 8 cols register patch (outputs: 1x4)
    #pragma unroll
    for (int r = 0; r < 5; r++) {
      float4 q0 = *(const float4*)&zt[(ly+r)*36 + lx4];
      float4 q1 = *(const float4*)&zt[(ly+r)*36 + lx4 + 4];
      zp[r*8+0]=q0.x; zp[r*8+1]=q0.y; zp[r*8+2]=q0.z; zp[r*8+3]=q0.w;
      zp[r*8+4]=q1.x; zp[r*8+5]=q1.y; zp[r*8+6]=q1.z; zp[r*8+7]=q1.w;
    }
    #pragma unroll
    for (int j = 0; j < 4; j++) {
      float ca = 0.f, cb = 0.f;
      #pragma unroll
      for (int u = 0; u < 5; u++)
        #pragma unroll
        for (int v = 0; v < 5; v++) {
          float zv = zp[u*8 + j + v];
          ca += zv*wa[u*5+v];
          cb += zv*wb[u*5+v];
        }
      float av = ca*sa + Ca; av = (av >= 0.f) ? av : 0.01f*av;
      float bv = cb*sb + Cb; bv = (bv >= 0.f) ? bv : 0.01f*bv;
      accA[j] += av; accB[j] += bv;
    }
  }
  int oy = ty0 + ly, ox = tx0 + lx4;
  size_t baseA = ((size_t)(b*64 + c)*256 + oy)*256 + ox;
  size_t baseB = ((size_t)(b*64 + 32 + c)*256 + oy)*256 + ox;
  *(float4*)&score[baseA] = make_float4(accA[0],accA[1],accA[2],accA[3]);
  *(float4*)&score[baseB] = make_float4(accB[0],accB[1],accB[2],accB[3]);
}

// ---------------- ft pass: BN -> MaxLeakyReLU -> BN -> EmphaseLocal ----------------
__global__ __launch_bounds__(256) void k_ft(const float* __restrict__ in,
                                            float* __restrict__ out,
                                            const float* __restrict__ P, float scale) {
  __shared__ float A[74*76];   // pointwise(y) with halo 5, zero outside image
  __shared__ float Bf[64*76];  // vertical 11-sums
  int tid = threadIdx.x;
  int c = blockIdx.y, b = blockIdx.z;
  int ty0 = (blockIdx.x >> 2)*64, tx0 = (blockIdx.x & 3)*64;
  float fs1 = P[1312+c], fc1 = P[1376+c], fs2 = P[1440+c], fc2 = P[1504+c];
  const float* ip = in + (size_t)(b*64 + c)*65536;
  for (int k = tid; k < 74*74; k += 256) {
    int ay = k/74, ax = k - ay*74;
    int gy = ty0 + ay - 5, gx = tx0 + ax - 5;
    float y = 0.f;
    if ((unsigned)gy < 256u && (unsigned)gx < 256u) {
      float v = ip[gy*256 + gx];
      float t = v*fs1 + fc1;
      t = (t > 0.1f) ? t : 0.7f*t;     // MaxLeakyReLU(0.7, 0.1)
      y = t*fs2 + fc2;
    }
    A[ay*76 + ax] = y;
  }
  __syncthreads();
  for (int task = tid; task < 296; task += 256) {     // 74 cols x 4 chunks of 16 rows
    int chunk = task/74; int col = task - chunk*74;
    int r0 = chunk*16;
    float s = 0.f;
    #pragma unroll
    for (int u = 0; u < 11; u++) s += A[(r0+u)*76 + col];
    Bf[r0*76 + col] = s;
    #pragma unroll
    for (int r = 1; r < 16; r++) {
      s += A[(r0+r+10)*76 + col] - A[(r0+r-1)*76 + col];
      Bf[(r0+r)*76 + col] = s;
    }
  }
  __syncthreads();
  {
    int r = tid >> 2; int c0 = (tid & 3)*16;          // 64 rows x 4 chunks of 16 cols
    float s = 0.f;
    #pragma unroll
    for (int v = 0; v < 11; v++) s += Bf[r*76 + c0 + v];
    float* op = out + (size_t)(b*64 + c)*65536 + (size_t)(ty0+r)*256 + tx0;
    float4 buf;
    #pragma unroll
    for (int j = 0; j < 16; j++) {
      float mean = s*(1.f/121.f);
      float y = A[(r+5)*76 + c0 + j + 5];
      float sig = 1.f/(1.f + expf(-(y - mean)));
      ((float*)&buf)[j & 3] = y*sig*scale;
      if ((j & 3) == 3) *(float4*)(op + c0 + (j & ~3)) = buf;
      if (j < 15) s += Bf[r*76 + c0 + j + 11] - Bf[r*76 + c0 + j];
    }
  }
}

// ---------------- launch ----------------
extern "C" void kernel_launch(void* const* d_in, const int* in_sizes, int n_in,
                              void* d_out, int out_size, void* d_ws, size_t ws_size,
                              hipStream_t stream) {
  const float* x = (const float*)d_in[0];
  float* ws = (float*)d_ws;
  float* out = (float*)d_out;

  PrepArgs pa;
  for (int i = 0; i < 39; i++) pa.p[i] = (const float*)d_in[i];
  k_prep<<<dim3(1), dim3(256), 0, stream>>>(pa, ws);

  k_mode_mlp<<<dim3(16,16,4), dim3(16,16), 0, stream>>>(x, ws, ws + P_D);

  const float* scw = (const float*)d_in[17];
  const float* scb = (const float*)d_in[18];
  const int hs[6] = {248, 83, 28, 10, 4, 2};
  const size_t offs[6] = {P_D, P_D1, P_D2, P_D3, P_D4, P_D5};
  for (int i = 0; i < 5; i++) {
    int total = 128*hs[i+1]*hs[i+1];
    k_down<<<dim3((total+255)/256), dim3(256), 0, stream>>>(ws + offs[i], ws + offs[i+1],
                                                            hs[i], hs[i+1], total, scw, scb);
  }

  k_accum<<<dim3(64,32,4), dim3(256), 0, stream>>>(ws, (const float*)d_in[19],
                                                   (const float*)d_in[25], ws + P_SCORE);

  // ft x3, ping-pong ws_score <-> d_out; /5 folded into last pass
  k_ft<<<dim3(16,64,4), dim3(256), 0, stream>>>(ws + P_SCORE, out, ws, 1.f);
  k_ft<<<dim3(16,64,4), dim3(256), 0, stream>>>(out, ws + P_SCORE, ws, 1.f);
  k_ft<<<dim3(16,64,4), dim3(256), 0, stream>>>(ws + P_SCORE, out, ws, 0.2f);
}